// Round 7
// baseline (300.645 us; speedup 1.0000x reference)
//
#include <hip/hip_runtime.h>
#include <hip/hip_fp16.h>
#include <math.h>

#define SRLEN   640000
#define NFRAMES 2501
#define FPB     8
#define SPAN    (256*(FPB-1) + 1024)   // 2816
#define MROW    520                    // padded mag row in halfs (513 used)
#define MAXW    48                     // max mel filter width in bins (actual max ~28)

__device__ __forceinline__ int rev6(int x) { return (int)(__brev((unsigned)x) >> 26); }

// precomputed per-launch tables
__device__ float2 g_tw512[256];     // exp(-i*pi*j/256)
__device__ float2 g_twu[512];       // exp(-i*pi*k/512)
__device__ int    g_fbs[128];       // first bin per mel (forced even)
__device__ int    g_fbc[128];       // bin count per mel
__device__ float  g_fbw[MAXW][128]; // compact weights, transposed for coalescing

// -------- K0: twiddle tables + sparse filterbank compaction (128 blocks) --------
__global__ __launch_bounds__(256)
void pcen_setup_kernel(const float* __restrict__ fb)
{
    const int tid = threadIdx.x;
    const int m   = blockIdx.x;

    if (m == 0) {
        float s, c;
        __sincosf(-3.14159265358979323846f * (float)tid / 256.0f, &s, &c);
        g_tw512[tid] = make_float2(c, s);
    }
    if (m == 1) {
        for (int k = tid; k < 512; k += 256) {
            float s, c;
            __sincosf(-3.14159265358979323846f * (float)k / 512.0f, &s, &c);
            g_twu[k] = make_float2(c, s);
        }
    }

    __shared__ int smn[256], smx[256];
    int s = 0x7fffffff, e = -1;
    for (int f = tid; f < 513; f += 256) {
        if (fb[f * 128 + m] != 0.0f) { s = min(s, f); e = max(e, f); }
    }
    smn[tid] = s; smx[tid] = e;
    __syncthreads();
    for (int o = 128; o > 0; o >>= 1) {
        if (tid < o) {
            smn[tid] = min(smn[tid], smn[tid + o]);
            smx[tid] = max(smx[tid], smx[tid + o]);
        }
        __syncthreads();
    }
    int S   = (smx[0] < 0) ? 0 : (smn[0] & ~1);           // force even start
    int cnt = (smx[0] < 0) ? 0 : (smx[0] - S + 1);
    if (cnt > MAXW) cnt = MAXW;
    if (tid == 0) { g_fbs[m] = S; g_fbc[m] = cnt; }
    for (int k = tid; k < cnt; k += 256)
        g_fbw[k][m] = fb[(S + k) * 128 + m];
}

// -------- K1: frames -> windowed rFFT magnitude (fp16) -> mel energies E[b][m][t] --------
__global__ __launch_bounds__(256)
void pcen_spec_kernel(const float* __restrict__ x, const float* __restrict__ win,
                      float* __restrict__ E)
{
    __shared__ __half span[SPAN];          // fp16 input span: 5.5 KB
    __shared__ __half mags[FPB][MROW];     // fp16 magnitudes: 8.1 KB

    const int tid = threadIdx.x;
    const int t0  = blockIdx.x * FPB;
    const int b   = blockIdx.y;

    // ---- load input span with reflect padding (fp16 store) ----
    const float* xb = x + (size_t)b * SRLEN;
    for (int j = tid; j < SPAN; j += 256) {
        int src = t0 * 256 + j - 512;
        src = (src < 0) ? -src : src;
        src = (src >= SRLEN) ? (2 * SRLEN - 2 - src) : src;
        span[j] = __float2half(xb[src]);
    }
    __syncthreads();

    const int lane = tid & 63;
    const int wid  = tid >> 6;
    const int lp   = rev6(lane);

    // each wave handles 2 frames, fully in registers (rolled loop, small I-footprint)
    for (int ff = 0; ff < 2; ++ff) {
        const int fr = wid * 2 + ff;
        float zre[8], zim[8];

        // pack: n = rg*64 + lane ; z[n] = xw[2n] + i*xw[2n+1]
        #pragma unroll
        for (int rg = 0; rg < 8; ++rg) {
            int n = rg * 64 + lane;
            __half2 sp = *(const __half2*)&span[fr * 256 + 2 * n];
            float2 w  = *(const float2*)&win[2 * n];
            zre[rg] = __half2float(sp.x) * w.x;
            zim[rg] = __half2float(sp.y) * w.y;
        }

        // ---- DIF stage m=256: pairs (r, r+4), j = rg*64+lane ----
        #pragma unroll
        for (int rg = 0; rg < 4; ++rg) {
            const float2 tw = g_tw512[rg * 64 + lane];
            float ar = zre[rg], ai = zim[rg], br = zre[rg + 4], bi = zim[rg + 4];
            zre[rg] = ar + br; zim[rg] = ai + bi;
            float dr = ar - br, di = ai - bi;
            zre[rg + 4] = dr * tw.x - di * tw.y;
            zim[rg + 4] = dr * tw.y + di * tw.x;
        }
        // ---- stage m=128: pairs (r, r+2) in each half, j = q*64+lane -> tw512[2j] ----
        #pragma unroll
        for (int h = 0; h < 2; ++h) {
            #pragma unroll
            for (int q = 0; q < 2; ++q) {
                int rt = h * 4 + q, rb = rt + 2;
                const float2 tw = g_tw512[(q * 64 + lane) * 2];
                float ar = zre[rt], ai = zim[rt], br = zre[rb], bi = zim[rb];
                zre[rt] = ar + br; zim[rt] = ai + bi;
                float dr = ar - br, di = ai - bi;
                zre[rb] = dr * tw.x - di * tw.y;
                zim[rb] = dr * tw.y + di * tw.x;
            }
        }
        // ---- stage m=64: pairs (r, r+1), j = lane -> tw512[4*lane] ----
        {
            const float2 tw = g_tw512[lane * 4];
            #pragma unroll
            for (int rt = 0; rt < 8; rt += 2) {
                int rb = rt + 1;
                float ar = zre[rt], ai = zim[rt], br = zre[rb], bi = zim[rb];
                zre[rt] = ar + br; zim[rt] = ai + bi;
                float dr = ar - br, di = ai - bi;
                zre[rb] = dr * tw.x - di * tw.y;
                zim[rb] = dr * tw.y + di * tw.x;
            }
        }
        // ---- 6 cross-lane stages: mask = 32..1, tw = tw512[(lane&(mask-1))*(256/mask)] ----
        #pragma unroll
        for (int st = 0; st < 6; ++st) {
            const int mask = 32 >> st;
            const float2 tw = g_tw512[(lane & (mask - 1)) * (256 / mask)];
            const bool bot = (lane & mask) != 0;
            const float cw = bot ? tw.x : 1.0f;
            const float sw = bot ? tw.y : 0.0f;
            const float sg = bot ? -1.0f : 1.0f;
            #pragma unroll
            for (int rg = 0; rg < 8; ++rg) {
                float orr = zre[rg], oii = zim[rg];
                float prr = __shfl_xor(orr, mask);
                float pri = __shfl_xor(oii, mask);
                float tr = prr + sg * orr;   // top: a+b ; bottom: a-b
                float ti = pri + sg * oii;
                zre[rg] = tr * cw - ti * sw;
                zim[rg] = tr * sw + ti * cw;
            }
        }

        // ---- reorder regs to natural Z order: lane holds Z[8*lp + q] ----
        float wre[8], wim[8];
        {
            const int R3[8] = {0, 4, 2, 6, 1, 5, 3, 7};
            #pragma unroll
            for (int q = 0; q < 8; ++q) { wre[q] = zre[R3[q]]; wim[q] = zim[R3[q]]; }
        }

        // ---- real-FFT unpack + magnitude, all via shuffles ----
        float pre[8], pim[8];
        #pragma unroll
        for (int q = 0; q < 8; ++q) {
            pre[q] = __shfl_xor(wre[q], 63);
            pim[q] = __shfl_xor(wim[q], 63);
        }
        const int q0v    = (64 - lp) & 63;
        const int p0lane = rev6(q0v);
        const float p0re = __shfl(wre[0], p0lane);
        const float p0im = __shfl(wim[0], p0lane);

        float mg[8];
        #pragma unroll
        for (int q = 0; q < 8; ++q) {
            float zr = wre[q], zi = wim[q];
            float mr = (q == 0) ? p0re : pre[8 - q];
            float mi = (q == 0) ? p0im : pim[8 - q];
            const float2 tw = g_twu[lp * 8 + q];
            float xer = 0.5f * (zr + mr), xei = 0.5f * (zi - mi);
            float xor_ = 0.5f * (zi + mi), xoi = 0.5f * (mr - zr);
            float xr = xer + tw.x * xor_ - tw.y * xoi;
            float xi = xei + tw.x * xoi + tw.y * xor_;
            mg[q] = sqrtf(xr * xr + xi * xi);
        }
        union { __half2 h2[4]; float4 f4; } pk;
        pk.h2[0] = __floats2half2_rn(mg[0], mg[1]);
        pk.h2[1] = __floats2half2_rn(mg[2], mg[3]);
        pk.h2[2] = __floats2half2_rn(mg[4], mg[5]);
        pk.h2[3] = __floats2half2_rn(mg[6], mg[7]);
        *(float4*)&mags[fr][lp * 8] = pk.f4;
        if (lane == 0) mags[fr][512] = __float2half(fabsf(wre[0] - wim[0]));  // Nyquist
    }
    __syncthreads();

    // ---- sparse mel projection: m = tid&127, fg = tid>>7 covers 4 frames ----
    const int m  = tid & 127;
    const int fg = tid >> 7;
    const int s0 = g_fbs[m];
    const int cn = g_fbc[m];
    float acc[4] = {0, 0, 0, 0};
    for (int k = 0; k < cn; ++k) {
        const float w = g_fbw[k][m];
        const int f = s0 + k;
        #pragma unroll
        for (int j = 0; j < 4; ++j)
            acc[j] = fmaf(w, __half2float(mags[fg * 4 + j][f]), acc[j]);
    }
    #pragma unroll
    for (int j = 0; j < 4; ++j) {
        int t = t0 + fg * 4 + j;
        if (t < NFRAMES)
            E[((size_t)(b * 128 + m)) * NFRAMES + t] = acc[j];
    }
}

// -------- K2: per-(b,m) IIR scan + PCEN nonlinearity, in place on E --------
__global__ __launch_bounds__(256)
void pcen_scan_kernel(float* __restrict__ E, const float* __restrict__ alpha,
                      const float* __restrict__ delta, const float* __restrict__ rr)
{
    __shared__ float sA[256], sB[256];
    __shared__ float row[2560];
    const int tid = threadIdx.x;
    const int bm  = blockIdx.x;
    const int m   = bm & 127;
    const size_t base = (size_t)bm * NFRAMES;

    const float al = alpha[m], de = delta[m], rp = rr[m];
    const float dpr = __powf(de, rp);

    // coalesced row load into LDS
    for (int t = tid; t < NFRAMES; t += 256) row[t] = E[base + t];
    if (tid < 2560 - NFRAMES) row[NFRAMES + tid] = 0.0f;
    __syncthreads();

    float e[10];
    #pragma unroll
    for (int j = 0; j < 10; ++j) e[j] = row[tid * 10 + j];

    // local fold of (a,b) pairs; identity (1,0) for padding
    float A = 1.0f, B = 0.0f;
    #pragma unroll
    for (int j = 0; j < 10; ++j) {
        int t = tid * 10 + j;
        bool v = t < NFRAMES;
        float a  = (t == 0) ? 1.0f : (v ? 0.96f : 1.0f);
        float bv = (t == 0) ? e[0] : (v ? 0.04f * e[j] : 0.0f);
        A *= a;
        B = a * B + bv;
    }
    sA[tid] = A; sB[tid] = B;
    __syncthreads();

    // Hillis-Steele inclusive scan over thread chunks
    for (int off = 1; off < 256; off <<= 1) {
        float a2 = sA[tid], b2 = sB[tid];
        float a1 = 1.0f, b1 = 0.0f;
        if (tid >= off) { a1 = sA[tid - off]; b1 = sB[tid - off]; }
        __syncthreads();
        sA[tid] = a1 * a2;
        sB[tid] = a2 * b1 + b2;
        __syncthreads();
    }
    float M = (tid > 0) ? sB[tid - 1] : 0.0f;   // carry: M before this chunk

    #pragma unroll
    for (int j = 0; j < 10; ++j) {
        int t = tid * 10 + j;
        bool v = t < NFRAMES;
        float a  = (t == 0) ? 1.0f : (v ? 0.96f : 1.0f);
        float bv = (t == 0) ? e[0] : (v ? 0.04f * e[j] : 0.0f);
        M = a * M + bv;
        if (v) {
            float inv = __powf(M + 1e-6f, -al);            // smooth^-1
            float val = fmaf(e[j], inv, de);
            row[t] = __powf(val, rp) - dpr;
        }
    }
    __syncthreads();

    // coalesced store
    for (int t = tid; t < NFRAMES; t += 256) E[base + t] = row[t];
}

extern "C" void kernel_launch(void* const* d_in, const int* in_sizes, int n_in,
                              void* d_out, int out_size, void* d_ws, size_t ws_size,
                              hipStream_t stream)
{
    const float* x     = (const float*)d_in[0];
    const float* alpha = (const float*)d_in[1];
    const float* delta = (const float*)d_in[2];
    const float* r     = (const float*)d_in[3];
    const float* fb    = (const float*)d_in[4];
    const float* win   = (const float*)d_in[5];
    float* out = (float*)d_out;

    pcen_setup_kernel<<<128, 256, 0, stream>>>(fb);
    dim3 g1((NFRAMES + FPB - 1) / FPB, 32);   // 313 x 32
    pcen_spec_kernel<<<g1, 256, 0, stream>>>(x, win, out);
    pcen_scan_kernel<<<32 * 128, 256, 0, stream>>>(out, alpha, delta, r);
}

// Round 8
// 268.233 us; speedup vs baseline: 1.1208x; 1.1208x over previous
//
#include <hip/hip_runtime.h>
#include <hip/hip_fp16.h>
#include <math.h>

#define SRLEN   640000
#define NFRAMES 2501
#define FPB     16
#define SPAN    (256*(FPB-1) + 1024)   // 4864
#define MROW    520                    // padded mag row in halfs (513 used)
#define MAXW    48                     // max mel filter width in bins (actual max ~28)

__device__ __forceinline__ int rev6(int x) { return (int)(__brev((unsigned)x) >> 26); }

// precomputed per-launch tables
__device__ float2 g_tw512[256];     // exp(-i*pi*j/256)
__device__ float2 g_twu[512];       // exp(-i*pi*k/512)
__device__ int    g_fbs[128];       // first bin per mel (forced even)
__device__ int    g_fbc[128];       // bin count per mel (forced even, zero-padded)
__device__ float  g_fbw[MAXW][128]; // compact weights, transposed for coalescing

// -------- K0: twiddle tables + sparse filterbank compaction (128 blocks) --------
__global__ __launch_bounds__(256)
void pcen_setup_kernel(const float* __restrict__ fb)
{
    const int tid = threadIdx.x;
    const int m   = blockIdx.x;

    if (m == 0) {
        float s, c;
        __sincosf(-3.14159265358979323846f * (float)tid / 256.0f, &s, &c);
        g_tw512[tid] = make_float2(c, s);
    }
    if (m == 1) {
        for (int k = tid; k < 512; k += 256) {
            float s, c;
            __sincosf(-3.14159265358979323846f * (float)k / 512.0f, &s, &c);
            g_twu[k] = make_float2(c, s);
        }
    }

    __shared__ int smn[256], smx[256];
    int s = 0x7fffffff, e = -1;
    for (int f = tid; f < 513; f += 256) {
        if (fb[f * 128 + m] != 0.0f) { s = min(s, f); e = max(e, f); }
    }
    smn[tid] = s; smx[tid] = e;
    __syncthreads();
    for (int o = 128; o > 0; o >>= 1) {
        if (tid < o) {
            smn[tid] = min(smn[tid], smn[tid + o]);
            smx[tid] = max(smx[tid], smx[tid + o]);
        }
        __syncthreads();
    }
    int S   = (smx[0] < 0) ? 0 : (smn[0] & ~1);           // force even start
    int cnt = (smx[0] < 0) ? 0 : (smx[0] - S + 1);
    if (cnt > MAXW) cnt = MAXW;
    int cntE = (cnt + 1) & ~1;                             // force even count
    if (tid == 0) { g_fbs[m] = S; g_fbc[m] = cntE; }
    for (int k = tid; k < cntE; k += 256)
        g_fbw[k][m] = (k < cnt) ? fb[(S + k) * 128 + m] : 0.0f;
}

// -------- K1: frames -> windowed rFFT magnitude (fp16) -> mel energies E[b][m][t] --------
__global__ __launch_bounds__(256)
void pcen_spec_kernel(const float* __restrict__ x, const float* __restrict__ win,
                      float* __restrict__ E)
{
    __shared__ float  span[SPAN];
    __shared__ __half mags[FPB][MROW];

    const int tid = threadIdx.x;
    const int t0  = blockIdx.x * FPB;
    const int b   = blockIdx.y;

    // ---- load input span with reflect padding ----
    const float* xb = x + (size_t)b * SRLEN;
    for (int j = tid; j < SPAN; j += 256) {
        int src = t0 * 256 + j - 512;
        src = (src < 0) ? -src : src;
        src = (src >= SRLEN) ? (2 * SRLEN - 2 - src) : src;
        span[j] = xb[src];
    }
    __syncthreads();

    const int lane = tid & 63;
    const int wid  = tid >> 6;
    const int lp   = rev6(lane);

    // ---- hoist ALL loop-invariant global loads into registers (lane-only deps) ----
    float2 twA[4], twB[2], twC, twS[6], twU[8], wv[8];
    #pragma unroll
    for (int rg = 0; rg < 4; ++rg) twA[rg] = g_tw512[rg * 64 + lane];
    #pragma unroll
    for (int q = 0; q < 2; ++q) twB[q] = g_tw512[(q * 64 + lane) * 2];
    twC = g_tw512[lane * 4];
    #pragma unroll
    for (int st = 0; st < 6; ++st) {
        const int mask = 32 >> st;
        twS[st] = g_tw512[(lane & (mask - 1)) * (256 / mask)];
    }
    #pragma unroll
    for (int q = 0; q < 8; ++q) twU[q] = g_twu[lp * 8 + q];
    #pragma unroll
    for (int rg = 0; rg < 8; ++rg) wv[rg] = *(const float2*)&win[2 * (rg * 64 + lane)];

    const int q0v    = (64 - lp) & 63;
    const int p0lane = rev6(q0v);

    // each wave handles 4 frames, fully in registers (rolled loop, small I-footprint)
    for (int ff = 0; ff < 4; ++ff) {
        const int fr = wid * 4 + ff;
        float zre[8], zim[8];

        // pack: n = rg*64 + lane ; z[n] = xw[2n] + i*xw[2n+1]
        #pragma unroll
        for (int rg = 0; rg < 8; ++rg) {
            float2 sp = *(const float2*)&span[fr * 256 + 2 * (rg * 64 + lane)];
            zre[rg] = sp.x * wv[rg].x;
            zim[rg] = sp.y * wv[rg].y;
        }

        // ---- DIF stage m=256: pairs (r, r+4) ----
        #pragma unroll
        for (int rg = 0; rg < 4; ++rg) {
            const float2 tw = twA[rg];
            float ar = zre[rg], ai = zim[rg], br = zre[rg + 4], bi = zim[rg + 4];
            zre[rg] = ar + br; zim[rg] = ai + bi;
            float dr = ar - br, di = ai - bi;
            zre[rg + 4] = dr * tw.x - di * tw.y;
            zim[rg + 4] = dr * tw.y + di * tw.x;
        }
        // ---- stage m=128: pairs (r, r+2) in each half ----
        #pragma unroll
        for (int h = 0; h < 2; ++h) {
            #pragma unroll
            for (int q = 0; q < 2; ++q) {
                int rt = h * 4 + q, rb = rt + 2;
                const float2 tw = twB[q];
                float ar = zre[rt], ai = zim[rt], br = zre[rb], bi = zim[rb];
                zre[rt] = ar + br; zim[rt] = ai + bi;
                float dr = ar - br, di = ai - bi;
                zre[rb] = dr * tw.x - di * tw.y;
                zim[rb] = dr * tw.y + di * tw.x;
            }
        }
        // ---- stage m=64: pairs (r, r+1) ----
        #pragma unroll
        for (int rt = 0; rt < 8; rt += 2) {
            int rb = rt + 1;
            float ar = zre[rt], ai = zim[rt], br = zre[rb], bi = zim[rb];
            zre[rt] = ar + br; zim[rt] = ai + bi;
            float dr = ar - br, di = ai - bi;
            zre[rb] = dr * twC.x - di * twC.y;
            zim[rb] = dr * twC.y + di * twC.x;
        }
        // ---- 6 cross-lane stages: mask = 32..1 ----
        #pragma unroll
        for (int st = 0; st < 6; ++st) {
            const int mask = 32 >> st;
            const float2 tw = twS[st];
            const bool bot = (lane & mask) != 0;
            const float cw = bot ? tw.x : 1.0f;
            const float sw = bot ? tw.y : 0.0f;
            const float sg = bot ? -1.0f : 1.0f;
            #pragma unroll
            for (int rg = 0; rg < 8; ++rg) {
                float orr = zre[rg], oii = zim[rg];
                float prr = __shfl_xor(orr, mask);
                float pri = __shfl_xor(oii, mask);
                float tr = prr + sg * orr;   // top: a+b ; bottom: a-b
                float ti = pri + sg * oii;
                zre[rg] = tr * cw - ti * sw;
                zim[rg] = tr * sw + ti * cw;
            }
        }

        // natural Z order: lane lp holds Z[8*lp + q] at reg R3[q]
        // R3 = {0,4,2,6,1,5,3,7}
        #define WRE(q) zre[(q)==0?0:(q)==1?4:(q)==2?2:(q)==3?6:(q)==4?1:(q)==5?5:(q)==6?3:7]
        #define WIM(q) zim[(q)==0?0:(q)==1?4:(q)==2?2:(q)==3?6:(q)==4?1:(q)==5?5:(q)==6?3:7]

        float mg[8];
        // helper: compute one magnitude given mirror values
        #define MAG(q, MR, MI) { \
            float zr = WRE(q), zi = WIM(q); \
            float mr = (MR), mi = (MI); \
            const float2 tw = twU[q]; \
            float xer = 0.5f * (zr + mr), xei = 0.5f * (zi - mi); \
            float xo  = 0.5f * (zi + mi), xoi = 0.5f * (mr - zr); \
            float xr = xer + tw.x * xo - tw.y * xoi; \
            float xi = xei + tw.x * xoi + tw.y * xo; \
            mg[q] = sqrtf(xr * xr + xi * xi); }

        // q=0: mirror from lane p0lane
        {
            float p0re = __shfl(WRE(0), p0lane);
            float p0im = __shfl(WIM(0), p0lane);
            MAG(0, p0re, p0im)
        }
        // q=4: self-mirror pair
        {
            float pr = __shfl_xor(WRE(4), 63);
            float pi = __shfl_xor(WIM(4), 63);
            MAG(4, pr, pi)
        }
        // pairs (1,7),(2,6),(3,5): mg[q] uses shfl of W(8-q); mg[8-q] uses shfl of W(q)
        #pragma unroll
        for (int q = 1; q <= 3; ++q) {
            float prq  = __shfl_xor(WRE(q), 63);
            float piq  = __shfl_xor(WIM(q), 63);
            float prq8 = __shfl_xor(WRE(8 - q), 63);
            float piq8 = __shfl_xor(WIM(8 - q), 63);
            MAG(q, prq8, piq8)
            MAG(8 - q, prq, piq)
        }
        #undef MAG
        #undef WRE
        #undef WIM

        union { __half2 h2[4]; float4 f4; } pk;
        pk.h2[0] = __floats2half2_rn(mg[0], mg[1]);
        pk.h2[1] = __floats2half2_rn(mg[2], mg[3]);
        pk.h2[2] = __floats2half2_rn(mg[4], mg[5]);
        pk.h2[3] = __floats2half2_rn(mg[6], mg[7]);
        *(float4*)&mags[fr][lp * 8] = pk.f4;
        if (lane == 0) {
            mags[fr][512] = __float2half(fabsf(zre[0] - zim[0]));  // Nyquist (R3[0]=0)
            mags[fr][513] = __float2half(0.0f);                    // pad for half2 mel reads
        }
    }
    __syncthreads();

    // ---- sparse mel projection via half2: m = tid&127, fg = tid>>7 covers 8 frames ----
    const int m  = tid & 127;
    const int fg = tid >> 7;
    const int s0 = g_fbs[m];   // even
    const int cn = g_fbc[m];   // even
    float acc[8] = {0, 0, 0, 0, 0, 0, 0, 0};
    for (int k = 0; k < cn; k += 2) {
        const float w0 = g_fbw[k][m];
        const float w1 = g_fbw[k + 1][m];
        const int f = s0 + k;
        #pragma unroll
        for (int j = 0; j < 8; ++j) {
            const __half2 h = *(const __half2*)&mags[fg * 8 + j][f];
            acc[j] = fmaf(w0, __half2float(h.x), fmaf(w1, __half2float(h.y), acc[j]));
        }
    }
    #pragma unroll
    for (int j = 0; j < 8; ++j) {
        int t = t0 + fg * 8 + j;
        if (t < NFRAMES)
            E[((size_t)(b * 128 + m)) * NFRAMES + t] = acc[j];
    }
}

// -------- K2: per-(b,m) IIR scan + PCEN nonlinearity, in place on E --------
__global__ __launch_bounds__(256)
void pcen_scan_kernel(float* __restrict__ E, const float* __restrict__ alpha,
                      const float* __restrict__ delta, const float* __restrict__ rr)
{
    __shared__ float sA[256], sB[256];
    __shared__ float row[2560];
    const int tid = threadIdx.x;
    const int bm  = blockIdx.x;
    const int m   = bm & 127;
    const size_t base = (size_t)bm * NFRAMES;

    const float al = alpha[m], de = delta[m], rp = rr[m];
    const float dpr = __powf(de, rp);

    // coalesced row load into LDS
    for (int t = tid; t < NFRAMES; t += 256) row[t] = E[base + t];
    if (tid < 2560 - NFRAMES) row[NFRAMES + tid] = 0.0f;
    __syncthreads();

    float e[10];
    #pragma unroll
    for (int j = 0; j < 10; ++j) e[j] = row[tid * 10 + j];

    // local fold of (a,b) pairs; identity (1,0) for padding
    float A = 1.0f, B = 0.0f;
    #pragma unroll
    for (int j = 0; j < 10; ++j) {
        int t = tid * 10 + j;
        bool v = t < NFRAMES;
        float a  = (t == 0) ? 1.0f : (v ? 0.96f : 1.0f);
        float bv = (t == 0) ? e[0] : (v ? 0.04f * e[j] : 0.0f);
        A *= a;
        B = a * B + bv;
    }
    sA[tid] = A; sB[tid] = B;
    __syncthreads();

    // Hillis-Steele inclusive scan over thread chunks
    for (int off = 1; off < 256; off <<= 1) {
        float a2 = sA[tid], b2 = sB[tid];
        float a1 = 1.0f, b1 = 0.0f;
        if (tid >= off) { a1 = sA[tid - off]; b1 = sB[tid - off]; }
        __syncthreads();
        sA[tid] = a1 * a2;
        sB[tid] = a2 * b1 + b2;
        __syncthreads();
    }
    float M = (tid > 0) ? sB[tid - 1] : 0.0f;   // carry: M before this chunk

    #pragma unroll
    for (int j = 0; j < 10; ++j) {
        int t = tid * 10 + j;
        bool v = t < NFRAMES;
        float a  = (t == 0) ? 1.0f : (v ? 0.96f : 1.0f);
        float bv = (t == 0) ? e[0] : (v ? 0.04f * e[j] : 0.0f);
        M = a * M + bv;
        if (v) {
            float inv = __powf(M + 1e-6f, -al);            // smooth^-1
            float val = fmaf(e[j], inv, de);
            row[t] = __powf(val, rp) - dpr;
        }
    }
    __syncthreads();

    // coalesced store
    for (int t = tid; t < NFRAMES; t += 256) E[base + t] = row[t];
}

extern "C" void kernel_launch(void* const* d_in, const int* in_sizes, int n_in,
                              void* d_out, int out_size, void* d_ws, size_t ws_size,
                              hipStream_t stream)
{
    const float* x     = (const float*)d_in[0];
    const float* alpha = (const float*)d_in[1];
    const float* delta = (const float*)d_in[2];
    const float* r     = (const float*)d_in[3];
    const float* fb    = (const float*)d_in[4];
    const float* win   = (const float*)d_in[5];
    float* out = (float*)d_out;

    pcen_setup_kernel<<<128, 256, 0, stream>>>(fb);
    dim3 g1((NFRAMES + FPB - 1) / FPB, 32);   // 157 x 32
    pcen_spec_kernel<<<g1, 256, 0, stream>>>(x, win, out);
    pcen_scan_kernel<<<32 * 128, 256, 0, stream>>>(out, alpha, delta, r);
}